// Round 9
// baseline (208.431 us; speedup 1.0000x reference)
//
#include <hip/hip_runtime.h>

#define NMEM 16384
#define MDIM 225
#define L1D 134
#define MCLS 4489     // 67*67 real positions per class
#define PPAD 4608     // 144*32 padded positions
#define NBLK 256      // 64-n tiles
#define MARGIN 0.5f

typedef __attribute__((ext_vector_type(8))) _Float16 f16x8;
typedef __attribute__((ext_vector_type(16))) float f32x16;

__device__ inline unsigned short f2h(float f) {
    const _Float16 h = (_Float16)f;
    unsigned short u; __builtin_memcpy(&u, &h, 2); return u;
}
__device__ inline _Float16 us2h(unsigned short u) {
    _Float16 h; __builtin_memcpy(&h, &u, 2); return h;
}
__device__ inline float h2f(unsigned short u) { return (float)us2h(u); }

// ---------------------------------------------------------------------------
// P0: collapsed filters -> fp16 (for MFMA) and fp32 (for exact rescue).
// One thread per (cls, n, k); layout [gid] with gid=(cls*NMEM+n)*64+k.
// ---------------------------------------------------------------------------
__global__ __launch_bounds__(256) void prep_cm(const float* __restrict__ mem,
                                               unsigned short* __restrict__ cmh,
                                               float* __restrict__ cm32) {
    const int gid = blockIdx.x * 256 + threadIdx.x;   // 4*16384*64 = 2^22
    const int k = gid & 63, n = (gid >> 6) & (NMEM - 1), cls = gid >> 20;
    const int u = k >> 3, v = k & 7, er = cls >> 1, ec = cls & 1;
    const int i0 = 2 * u - er, j0 = 2 * v - ec;
    const float* mrow = mem + (size_t)n * MDIM;
    float s = 0.f;
    #pragma unroll
    for (int di = 0; di < 2; ++di) {
        const int i = i0 + di;
        if ((unsigned)i >= 15u) continue;
        #pragma unroll
        for (int dj = 0; dj < 2; ++dj) {
            const int j = j0 + dj;
            if ((unsigned)j >= 15u) continue;
            s += mrow[i * 15 + j];
        }
    }
    cmh[gid] = f2h(s);
    cm32[gid] = s;
}

// ---------------------------------------------------------------------------
// P1: hn[n] = 0.5*||mem_n||^2 (f32 for rescue) + packed fp16 (-hn_hi,-hn_lo)
// for the GEMM-folded subtraction. One wave per n.
// ---------------------------------------------------------------------------
__global__ __launch_bounds__(256) void prep_hn(const float* __restrict__ mem,
                                               float* __restrict__ hn,
                                               unsigned int* __restrict__ hnb) {
    const int wave = threadIdx.x >> 6, lane = threadIdx.x & 63;
    const int n = blockIdx.x * 4 + wave;
    const float* mrow = mem + (size_t)n * MDIM;
    float s = 0.f;
    for (int t = lane; t < MDIM; t += 64) { const float v = mrow[t]; s += v * v; }
    #pragma unroll
    for (int m = 1; m < 64; m <<= 1) s += __shfl_xor(s, m);
    if (lane == 0) {
        const float h = 0.5f * s;
        hn[n] = h;
        const unsigned short nh = f2h(-h);
        const unsigned short nl = f2h(-h - h2f(nh));
        hnb[n] = (unsigned)nh | ((unsigned)nl << 16);
    }
}

// ---------------------------------------------------------------------------
// P2: X (positions) in B-fragment layout, fp16: x[(pt*4+ks)*2+g][lane32][8j].
// ---------------------------------------------------------------------------
__global__ __launch_bounds__(256) void prep_x(const float* __restrict__ img,
                                              unsigned short* __restrict__ xh) {
    const int t = blockIdx.x * 256 + threadIdx.x;   // 144*4*2*32 = 36864
    const int nl = t & 31, g = (t >> 5) & 1, ks = (t >> 6) & 3, pt = t >> 8;
    const int pos = pt * 32 + nl;
    const int u = ks * 2 + g;
    unsigned short h[8];
    if (pos < MCLS) {
        const int mr = pos / 67, mc = pos - mr * 67;
        const int r = mr - 5 + u;
        #pragma unroll
        for (int j = 0; j < 8; ++j) {
            const int c = mc - 5 + j;
            float v = 0.f;
            if ((unsigned)r < 64u && (unsigned)c < 64u) v = img[r * 64 + c];
            h[j] = f2h(v);
        }
    } else {
        #pragma unroll
        for (int j = 0; j < 8; ++j) h[j] = 0;
    }
    #pragma unroll
    for (int j = 0; j < 8; ++j) xh[(size_t)t * 8 + j] = h[j];
}

// ---------------------------------------------------------------------------
// K1: fp16 MFMA scoring. Grid (256 nblk, 4 cls), 4 waves, (256,4) bounds.
// A (64 n x 64 k) register-resident; -hn folded via fp16 hi/lo ext K-slice.
// B double-buffered in registers (pt = it*4+wave => +8192 halves/iter).
// Epilogue: plain fmax over 64 n (no ids — rescue rescans candidate tiles),
// coalesced 4B store pcv[(cls*NBLK+nblk)*PPAD + pos].
// A/B frag: row=lane&31, k=(lane>>5)*8+j. C/D: col=lane&31,
// row=(r&3)+8*(r>>2)+4*(lane>>5)  [HW-verified].
// ---------------------------------------------------------------------------
__global__ __launch_bounds__(256, 4) void mfma_argmin_kernel(const unsigned short* __restrict__ cmh,
                                                             const unsigned short* __restrict__ xh,
                                                             const unsigned int* __restrict__ hnb,
                                                             float* __restrict__ pcv) {
    const int nblk = blockIdx.x, cls = blockIdx.y;
    const int t = threadIdx.x, wave = t >> 6, lane = t & 63;
    const int g = lane >> 5, nl = lane & 31;

    f16x8 a0[4], a1[4];
    #pragma unroll
    for (int ks = 0; ks < 4; ++ks) {
        const size_t base = ((size_t)(cls * NMEM + nblk * 64 + nl)) * 64 + ks * 16 + g * 8;
        a0[ks] = *(const f16x8*)(cmh + base);
        a1[ks] = *(const f16x8*)(cmh + base + 32 * 64);
    }

    const unsigned int hp0 = hnb[nblk * 64 + nl];
    const unsigned int hp1 = hnb[nblk * 64 + 32 + nl];
    f16x8 aex0 = {0,0,0,0,0,0,0,0}, aex1 = {0,0,0,0,0,0,0,0}, bex = {0,0,0,0,0,0,0,0};
    if (g == 0) {
        aex0[0] = us2h((unsigned short)(hp0 & 0xFFFFu));
        aex0[1] = us2h((unsigned short)(hp0 >> 16));
        aex1[0] = us2h((unsigned short)(hp1 & 0xFFFFu));
        aex1[1] = us2h((unsigned short)(hp1 >> 16));
        bex[0] = (_Float16)1.0f;
        bex[1] = (_Float16)1.0f;
    }

    const unsigned short* xp = xh + ((size_t)((wave * 4) * 2 + g)) * 256 + nl * 8;
    float* const orow = pcv + (size_t)(cls * NBLK + nblk) * PPAD;

    f16x8 bcur[4], bnxt[4];
    #pragma unroll
    for (int ks = 0; ks < 4; ++ks) bcur[ks] = *(const f16x8*)(xp + ks * 512);

    for (int it = 0; it < 36; ++it) {
        if (it < 35) {
            const unsigned short* xn = xp + 8192;
            #pragma unroll
            for (int ks = 0; ks < 4; ++ks) bnxt[ks] = *(const f16x8*)(xn + ks * 512);
        }

        f32x16 acc0 = {0.f,0.f,0.f,0.f,0.f,0.f,0.f,0.f,0.f,0.f,0.f,0.f,0.f,0.f,0.f,0.f};
        f32x16 acc1 = {0.f,0.f,0.f,0.f,0.f,0.f,0.f,0.f,0.f,0.f,0.f,0.f,0.f,0.f,0.f,0.f};
        #pragma unroll
        for (int ks = 0; ks < 4; ++ks) {
            acc0 = __builtin_amdgcn_mfma_f32_32x32x16_f16(a0[ks], bcur[ks], acc0, 0, 0, 0);
            acc1 = __builtin_amdgcn_mfma_f32_32x32x16_f16(a1[ks], bcur[ks], acc1, 0, 0, 0);
        }
        acc0 = __builtin_amdgcn_mfma_f32_32x32x16_f16(aex0, bex, acc0, 0, 0, 0);
        acc1 = __builtin_amdgcn_mfma_f32_32x32x16_f16(aex1, bex, acc1, 0, 0, 0);

        // Epilogue: plain max over 64 n.
        float pm = -3.0e38f;
        #pragma unroll
        for (int r = 0; r < 16; ++r) {
            pm = fmaxf(pm, acc0[r]);
            pm = fmaxf(pm, acc1[r]);
        }
        pm = fmaxf(pm, __shfl_xor(pm, 32));

        if (g == 0) orow[(it * 4 + wave) * 32 + nl] = pm;

        xp += 8192;
        #pragma unroll
        for (int ks = 0; ks < 4; ++ks) bcur[ks] = bnxt[ks];
    }
}

// ---------------------------------------------------------------------------
// K2: rescue, one wave per (cls, pos). Reads 256 tile-maxes (4/lane, strided
// — L2-reused across the 16 neighboring-pos waves per line), shfl-max vmax,
// ballot tiles within MARGIN, exact fp32 rescore of ALL 64 n per candidate
// tile from cm32 (lane n = nblk*64+lane, x broadcast via shfl). Butterfly
// argmax with lowest-n tie, matching argmin-first semantics.
// ---------------------------------------------------------------------------
__global__ __launch_bounds__(256) void rescue_kernel(const float* __restrict__ img,
                                                     const float* __restrict__ cm32,
                                                     const float* __restrict__ hn,
                                                     const float* __restrict__ pcv,
                                                     int* __restrict__ idx2d) {
    const int wave = threadIdx.x >> 6, lane = threadIdx.x & 63;
    const int cls = blockIdx.y;
    const int pos = blockIdx.x * 4 + wave;
    if (pos >= MCLS) return;
    const int er = cls >> 1, ec = cls & 1;
    const int mr = pos / 67, mc = pos - mr * 67;

    // per-lane x value, lane = u*8+v == k index of the collapsed filters.
    const int xr = mr - 5 + (lane >> 3), xc = mc - 5 + (lane & 7);
    const float xv = ((unsigned)xr < 64u && (unsigned)xc < 64u) ? img[xr * 64 + xc] : 0.f;

    // vals[s] = tile-max of nblk = lane*4+s.
    const float* col = pcv + (size_t)cls * NBLK * PPAD + pos;
    float vals[4];
    #pragma unroll
    for (int s = 0; s < 4; ++s) vals[s] = col[(size_t)(lane * 4 + s) * PPAD];

    float vmax = fmaxf(fmaxf(vals[0], vals[1]), fmaxf(vals[2], vals[3]));
    #pragma unroll
    for (int m = 1; m < 64; m <<= 1) vmax = fmaxf(vmax, __shfl_xor(vmax, m));
    const float thr = vmax - MARGIN;

    float best = -3.0e38f; int bn = 0x7FFFFFFF;
    #pragma unroll
    for (int s = 0; s < 4; ++s) {
        unsigned long long bal = __ballot(vals[s] >= thr);
        while (bal) {
            const int src = __ffsll((long long)bal) - 1;
            bal &= bal - 1;
            const int nblk = src * 4 + s;
            const int n = nblk * 64 + lane;                 // this lane's row
            const float* crow = cm32 + ((size_t)(cls * NMEM + n)) * 64;
            float sc = 0.f;
            #pragma unroll
            for (int c = 0; c < 16; ++c) {
                const float4 cv = *(const float4*)(crow + c * 4);
                sc = fmaf(cv.x, __shfl(xv, c * 4 + 0), sc);
                sc = fmaf(cv.y, __shfl(xv, c * 4 + 1), sc);
                sc = fmaf(cv.z, __shfl(xv, c * 4 + 2), sc);
                sc = fmaf(cv.w, __shfl(xv, c * 4 + 3), sc);
            }
            sc -= hn[n];
            if (sc > best || (sc == best && n < bn)) { best = sc; bn = n; }
        }
    }
    // Butterfly argmax (tie -> lowest n).
    #pragma unroll
    for (int m = 1; m < 64; m <<= 1) {
        const float ob = __shfl_xor(best, m);
        const int onb = __shfl_xor(bn, m);
        if (ob > best || (ob == best && onb < bn)) { best = ob; bn = onb; }
    }
    if (lane == 0) idx2d[(er + 2 * mr) * L1D + (ec + 2 * mc)] = bn;
}

// ---------------------------------------------------------------------------
// K3: fold, one wave per output pixel.
// ---------------------------------------------------------------------------
__global__ __launch_bounds__(256) void fold_kernel(const float* __restrict__ mem,
                                                   const int* __restrict__ idx2d,
                                                   float* __restrict__ outraw) {
    const int wave = threadIdx.x >> 6, lane = threadIdx.x & 63;
    const int p = blockIdx.x * 4 + wave;   // 0..4095
    const int oi = p >> 6, oj = p & 63;
    float s = 0.f;
    #pragma unroll
    for (int tb = 0; tb < 256; tb += 64) {
        const int tt = tb + lane;
        if (tt < MDIM) {
            const int a = tt / 15, b = tt - 15 * a;
            const int r = 10 + 2 * oi - a, c = 10 + 2 * oj - b;
            if ((unsigned)r < (unsigned)L1D && (unsigned)c < (unsigned)L1D) {
                const int n = idx2d[r * L1D + c];
                s += mem[(size_t)n * MDIM + tt];
            }
        }
    }
    #pragma unroll
    for (int msk = 1; msk < 64; msk <<= 1) s += __shfl_xor(s, msk);
    if (lane == 0) outraw[p] = s;
}

// ---------------------------------------------------------------------------
// K4: divide by global max (single block).
// ---------------------------------------------------------------------------
__global__ __launch_bounds__(256) void norm_kernel(const float* __restrict__ outraw,
                                                   float* __restrict__ out) {
    __shared__ float red[256];
    const int t = threadIdx.x;
    float m = -3.0e38f;
    #pragma unroll
    for (int i = 0; i < 16; ++i) m = fmaxf(m, outraw[t + i * 256]);
    red[t] = m;
    __syncthreads();
    for (int s = 128; s > 0; s >>= 1) {
        if (t < s) red[t] = fmaxf(red[t], red[t + s]);
        __syncthreads();
    }
    const float mx = red[0];
    #pragma unroll
    for (int i = 0; i < 16; ++i) out[t + i * 256] = outraw[t + i * 256] / mx;
}

extern "C" void kernel_launch(void* const* d_in, const int* in_sizes, int n_in,
                              void* d_out, int out_size, void* d_ws, size_t ws_size,
                              hipStream_t stream) {
    const float* img = (const float*)d_in[0];   // 64*64 fp32
    const float* mem = (const float*)d_in[1];   // 16384*225 fp32
    float* out = (float*)d_out;                 // 4096 fp32

    unsigned short* cmh = (unsigned short*)d_ws;              // 4*16384*64 ushort = 8.4 MB
    float* cm32 = (float*)(cmh + (size_t)4 * NMEM * 64);      // 16.8 MB
    float* hn = cm32 + (size_t)4 * NMEM * 64;                 // 16384 f
    unsigned int* hnb = (unsigned int*)(hn + NMEM);           // 16384 u32
    unsigned short* xh = (unsigned short*)(hnb + NMEM);       // 294912 ushort
    float* pcv = (float*)(xh + 294912);                       // 4*256*4608 f = 18.9 MB
    int* idx2d = (int*)(pcv + (size_t)4 * NBLK * PPAD);       // 17956 i
    float* outraw = (float*)(idx2d + L1D * L1D);              // 4096 f

    prep_cm<<<(4 * NMEM * 64) / 256, 256, 0, stream>>>(mem, cmh, cm32);
    prep_hn<<<NMEM / 4, 256, 0, stream>>>(mem, hn, hnb);
    prep_x<<<144, 256, 0, stream>>>(img, xh);
    mfma_argmin_kernel<<<dim3(NBLK, 4), 256, 0, stream>>>(cmh, xh, hnb, pcv);
    rescue_kernel<<<dim3((MCLS + 3) / 4, 4), 256, 0, stream>>>(img, cm32, hn, pcv, idx2d);
    fold_kernel<<<1024, 256, 0, stream>>>(mem, idx2d, outraw);
    norm_kernel<<<1, 256, 0, stream>>>(outraw, out);
}

// Round 10
// 184.645 us; speedup vs baseline: 1.1288x; 1.1288x over previous
//
#include <hip/hip_runtime.h>

#define NMEM 16384
#define MDIM 225
#define L1D 134
#define MCLS 4489     // 67*67 real positions per class
#define PPAD 4608     // 144*32 padded positions
#define NBLK 256      // 64-n tiles
#define MARGIN 0.5f

typedef __attribute__((ext_vector_type(8))) _Float16 f16x8;
typedef __attribute__((ext_vector_type(16))) float f32x16;

__device__ inline unsigned short f2h(float f) {
    const _Float16 h = (_Float16)f;
    unsigned short u; __builtin_memcpy(&u, &h, 2); return u;
}
__device__ inline _Float16 us2h(unsigned short u) {
    _Float16 h; __builtin_memcpy(&h, &u, 2); return h;
}
__device__ inline float h2f(unsigned short u) { return (float)us2h(u); }

// ---------------------------------------------------------------------------
// P0 (merged): one wave per n. Stage mem row (225 f) in LDS once; emit
// hn/hnb (wave reduce) and all 4 classes' collapsed filters (fp16 + fp32),
// coalesced 64-wide per class. Reads mem exactly once.
// ---------------------------------------------------------------------------
__global__ __launch_bounds__(256) void prep_all(const float* __restrict__ mem,
                                                unsigned short* __restrict__ cmh,
                                                float* __restrict__ cm32,
                                                float* __restrict__ hn,
                                                unsigned int* __restrict__ hnb) {
    __shared__ float lds[4][240];
    const int wave = threadIdx.x >> 6, lane = threadIdx.x & 63;
    const int n = blockIdx.x * 4 + wave;
    const float* mrow = mem + (size_t)n * MDIM;
    float nrm = 0.f;
    #pragma unroll
    for (int q = 0; q < 4; ++q) {
        const int tt = q * 64 + lane;
        if (tt < MDIM) {
            const float v = mrow[tt];
            lds[wave][tt] = v;
            nrm += v * v;
        }
    }
    __syncthreads();
    #pragma unroll
    for (int m = 1; m < 64; m <<= 1) nrm += __shfl_xor(nrm, m);
    if (lane == 0) {
        const float h = 0.5f * nrm;
        hn[n] = h;
        const unsigned short nh = f2h(-h);
        const unsigned short nl2 = f2h(-h - h2f(nh));
        hnb[n] = (unsigned)nh | ((unsigned)nl2 << 16);
    }
    const int u = lane >> 3, v = lane & 7;
    #pragma unroll
    for (int cls = 0; cls < 4; ++cls) {
        const int er = cls >> 1, ec = cls & 1;
        const int i0 = 2 * u - er, j0 = 2 * v - ec;
        float s = 0.f;
        #pragma unroll
        for (int di = 0; di < 2; ++di) {
            const int i = i0 + di;
            if ((unsigned)i >= 15u) continue;
            #pragma unroll
            for (int dj = 0; dj < 2; ++dj) {
                const int j = j0 + dj;
                if ((unsigned)j >= 15u) continue;
                s += lds[wave][i * 15 + j];
            }
        }
        const size_t o = ((size_t)(cls * NMEM + n)) * 64 + lane;
        cmh[o] = f2h(s);
        cm32[o] = s;
    }
}

// ---------------------------------------------------------------------------
// P2: X (positions) in B-fragment layout, fp16: x[(pt*4+ks)*2+g][lane32][8j].
// ---------------------------------------------------------------------------
__global__ __launch_bounds__(256) void prep_x(const float* __restrict__ img,
                                              unsigned short* __restrict__ xh) {
    const int t = blockIdx.x * 256 + threadIdx.x;   // 144*4*2*32 = 36864
    const int nl = t & 31, g = (t >> 5) & 1, ks = (t >> 6) & 3, pt = t >> 8;
    const int pos = pt * 32 + nl;
    const int u = ks * 2 + g;
    unsigned short h[8];
    if (pos < MCLS) {
        const int mr = pos / 67, mc = pos - mr * 67;
        const int r = mr - 5 + u;
        #pragma unroll
        for (int j = 0; j < 8; ++j) {
            const int c = mc - 5 + j;
            float v = 0.f;
            if ((unsigned)r < 64u && (unsigned)c < 64u) v = img[r * 64 + c];
            h[j] = f2h(v);
        }
    } else {
        #pragma unroll
        for (int j = 0; j < 8; ++j) h[j] = 0;
    }
    #pragma unroll
    for (int j = 0; j < 8; ++j) xh[(size_t)t * 8 + j] = h[j];
}

// ---------------------------------------------------------------------------
// K1: fp16 MFMA scoring, cls-paired to halve the xh L2 stream. Grid
// (256 nblk, 2): block handles cls = 2*cp and 2*cp+1 over the same B tiles.
// A register-resident for both classes; -hn ext K-slice shared (cls-indep).
// B double-buffered (pt = it*4+wave => +8192 halves/iter). Epilogue: plain
// fmax over 64 n per cls, coalesced 4B store pcv[(cls*NBLK+nblk)*PPAD+pos].
// A/B frag: row=lane&31, k=(lane>>5)*8+j. C/D: col=lane&31,
// row=(r&3)+8*(r>>2)+4*(lane>>5)  [HW-verified].
// ---------------------------------------------------------------------------
__global__ __launch_bounds__(256, 2) void mfma_argmin_kernel(const unsigned short* __restrict__ cmh,
                                                             const unsigned short* __restrict__ xh,
                                                             const unsigned int* __restrict__ hnb,
                                                             float* __restrict__ pcv) {
    const int nblk = blockIdx.x, cp = blockIdx.y;
    const int t = threadIdx.x, wave = t >> 6, lane = t & 63;
    const int g = lane >> 5, nl = lane & 31;

    f16x8 a[2][2][4];   // [cls-half][rowgroup][ks]
    #pragma unroll
    for (int h = 0; h < 2; ++h) {
        const int cls = cp * 2 + h;
        #pragma unroll
        for (int ks = 0; ks < 4; ++ks) {
            const size_t base = ((size_t)(cls * NMEM + nblk * 64 + nl)) * 64 + ks * 16 + g * 8;
            a[h][0][ks] = *(const f16x8*)(cmh + base);
            a[h][1][ks] = *(const f16x8*)(cmh + base + 32 * 64);
        }
    }

    const unsigned int hp0 = hnb[nblk * 64 + nl];
    const unsigned int hp1 = hnb[nblk * 64 + 32 + nl];
    f16x8 aex0 = {0,0,0,0,0,0,0,0}, aex1 = {0,0,0,0,0,0,0,0}, bex = {0,0,0,0,0,0,0,0};
    if (g == 0) {
        aex0[0] = us2h((unsigned short)(hp0 & 0xFFFFu));
        aex0[1] = us2h((unsigned short)(hp0 >> 16));
        aex1[0] = us2h((unsigned short)(hp1 & 0xFFFFu));
        aex1[1] = us2h((unsigned short)(hp1 >> 16));
        bex[0] = (_Float16)1.0f;
        bex[1] = (_Float16)1.0f;
    }

    const unsigned short* xp = xh + ((size_t)((wave * 4) * 2 + g)) * 256 + nl * 8;
    float* const orow0 = pcv + (size_t)((cp * 2 + 0) * NBLK + nblk) * PPAD;
    float* const orow1 = pcv + (size_t)((cp * 2 + 1) * NBLK + nblk) * PPAD;

    f16x8 bcur[4], bnxt[4];
    #pragma unroll
    for (int ks = 0; ks < 4; ++ks) bcur[ks] = *(const f16x8*)(xp + ks * 512);

    for (int it = 0; it < 36; ++it) {
        if (it < 35) {
            const unsigned short* xn = xp + 8192;
            #pragma unroll
            for (int ks = 0; ks < 4; ++ks) bnxt[ks] = *(const f16x8*)(xn + ks * 512);
        }

        f32x16 acc[2][2];
        #pragma unroll
        for (int h = 0; h < 2; ++h)
            #pragma unroll
            for (int rg = 0; rg < 2; ++rg)
                #pragma unroll
                for (int r = 0; r < 16; ++r) acc[h][rg][r] = 0.f;

        #pragma unroll
        for (int ks = 0; ks < 4; ++ks)
            #pragma unroll
            for (int h = 0; h < 2; ++h) {
                acc[h][0] = __builtin_amdgcn_mfma_f32_32x32x16_f16(a[h][0][ks], bcur[ks], acc[h][0], 0, 0, 0);
                acc[h][1] = __builtin_amdgcn_mfma_f32_32x32x16_f16(a[h][1][ks], bcur[ks], acc[h][1], 0, 0, 0);
            }
        #pragma unroll
        for (int h = 0; h < 2; ++h) {
            acc[h][0] = __builtin_amdgcn_mfma_f32_32x32x16_f16(aex0, bex, acc[h][0], 0, 0, 0);
            acc[h][1] = __builtin_amdgcn_mfma_f32_32x32x16_f16(aex1, bex, acc[h][1], 0, 0, 0);
        }

        const int pos = (it * 4 + wave) * 32 + nl;
        #pragma unroll
        for (int h = 0; h < 2; ++h) {
            float pm = -3.0e38f;
            #pragma unroll
            for (int r = 0; r < 16; ++r) {
                pm = fmaxf(pm, acc[h][0][r]);
                pm = fmaxf(pm, acc[h][1][r]);
            }
            pm = fmaxf(pm, __shfl_xor(pm, 32));
            if (g == 0) (h ? orow1 : orow0)[pos] = pm;
        }

        xp += 8192;
        #pragma unroll
        for (int ks = 0; ks < 4; ++ks) bcur[ks] = bnxt[ks];
    }
}

// ---------------------------------------------------------------------------
// T: transpose pcv (4, NBLK, PPAD) -> pcvT (4, PPAD, NBLK), float4 both
// global sides. Grid (PPAD/64, NBLK/64, 4).
// ---------------------------------------------------------------------------
__global__ __launch_bounds__(256) void transpose_kernel(const float* __restrict__ in,
                                                        float* __restrict__ out) {
    __shared__ float tile[64][65];
    const int pb = blockIdx.x, tb = blockIdx.y, cls = blockIdx.z;
    const int t = threadIdx.x;
    const int c4 = t & 15, r0 = t >> 4;
    #pragma unroll
    for (int rr = 0; rr < 4; ++rr) {
        const int row = r0 + rr * 16;
        const float4 v = *(const float4*)(in + ((size_t)(cls * NBLK + tb * 64 + row)) * PPAD + pb * 64 + c4 * 4);
        tile[row][c4 * 4 + 0] = v.x;
        tile[row][c4 * 4 + 1] = v.y;
        tile[row][c4 * 4 + 2] = v.z;
        tile[row][c4 * 4 + 3] = v.w;
    }
    __syncthreads();
    #pragma unroll
    for (int rr = 0; rr < 4; ++rr) {
        const int p = r0 + rr * 16;
        float4 v;
        v.x = tile[c4 * 4 + 0][p];
        v.y = tile[c4 * 4 + 1][p];
        v.z = tile[c4 * 4 + 2][p];
        v.w = tile[c4 * 4 + 3][p];
        *(float4*)(out + ((size_t)(cls * PPAD + pb * 64 + p)) * NBLK + tb * 64 + c4 * 4) = v;
    }
}

// ---------------------------------------------------------------------------
// K2: rescue, one wave per (cls, pos). Coalesced row read of 256 tile-maxes
// from pcvT, shfl-max vmax, ballot tiles within MARGIN, exact fp32 rescore
// of ALL 64 n per candidate tile from cm32 (lane n = nblk*64+lane, x
// broadcast via shfl). Butterfly argmax with lowest-n tie (argmin-first).
// ---------------------------------------------------------------------------
__global__ __launch_bounds__(256) void rescue_kernel(const float* __restrict__ img,
                                                     const float* __restrict__ cm32,
                                                     const float* __restrict__ hn,
                                                     const float* __restrict__ pcvT,
                                                     int* __restrict__ idx2d) {
    const int wave = threadIdx.x >> 6, lane = threadIdx.x & 63;
    const int cls = blockIdx.y;
    const int pos = blockIdx.x * 4 + wave;
    if (pos >= MCLS) return;
    const int er = cls >> 1, ec = cls & 1;
    const int mr = pos / 67, mc = pos - mr * 67;

    // per-lane x value, lane = u*8+v == k index of the collapsed filters.
    const int xr = mr - 5 + (lane >> 3), xc = mc - 5 + (lane & 7);
    const float xv = ((unsigned)xr < 64u && (unsigned)xc < 64u) ? img[xr * 64 + xc] : 0.f;

    // vals[s] = tile-max of nblk = lane*4+s  (contiguous row read).
    const float* row = pcvT + ((size_t)(cls * PPAD + pos)) * NBLK + lane * 4;
    const float4 v4 = *(const float4*)row;
    float vals[4] = {v4.x, v4.y, v4.z, v4.w};

    float vmax = fmaxf(fmaxf(vals[0], vals[1]), fmaxf(vals[2], vals[3]));
    #pragma unroll
    for (int m = 1; m < 64; m <<= 1) vmax = fmaxf(vmax, __shfl_xor(vmax, m));
    const float thr = vmax - MARGIN;

    float best = -3.0e38f; int bn = 0x7FFFFFFF;
    #pragma unroll
    for (int s = 0; s < 4; ++s) {
        unsigned long long bal = __ballot(vals[s] >= thr);
        while (bal) {
            const int src = __ffsll((long long)bal) - 1;
            bal &= bal - 1;
            const int nblk = src * 4 + s;
            const int n = nblk * 64 + lane;                 // this lane's row
            const float* crow = cm32 + ((size_t)(cls * NMEM + n)) * 64;
            float sc = 0.f;
            #pragma unroll
            for (int c = 0; c < 16; ++c) {
                const float4 cv = *(const float4*)(crow + c * 4);
                sc = fmaf(cv.x, __shfl(xv, c * 4 + 0), sc);
                sc = fmaf(cv.y, __shfl(xv, c * 4 + 1), sc);
                sc = fmaf(cv.z, __shfl(xv, c * 4 + 2), sc);
                sc = fmaf(cv.w, __shfl(xv, c * 4 + 3), sc);
            }
            sc -= hn[n];
            if (sc > best || (sc == best && n < bn)) { best = sc; bn = n; }
        }
    }
    #pragma unroll
    for (int m = 1; m < 64; m <<= 1) {
        const float ob = __shfl_xor(best, m);
        const int onb = __shfl_xor(bn, m);
        if (ob > best || (ob == best && onb < bn)) { best = ob; bn = onb; }
    }
    if (lane == 0) idx2d[(er + 2 * mr) * L1D + (ec + 2 * mc)] = bn;
}

// ---------------------------------------------------------------------------
// K3: fold, one wave per output pixel.
// ---------------------------------------------------------------------------
__global__ __launch_bounds__(256) void fold_kernel(const float* __restrict__ mem,
                                                   const int* __restrict__ idx2d,
                                                   float* __restrict__ outraw) {
    const int wave = threadIdx.x >> 6, lane = threadIdx.x & 63;
    const int p = blockIdx.x * 4 + wave;   // 0..4095
    const int oi = p >> 6, oj = p & 63;
    float s = 0.f;
    #pragma unroll
    for (int tb = 0; tb < 256; tb += 64) {
        const int tt = tb + lane;
        if (tt < MDIM) {
            const int a = tt / 15, b = tt - 15 * a;
            const int r = 10 + 2 * oi - a, c = 10 + 2 * oj - b;
            if ((unsigned)r < (unsigned)L1D && (unsigned)c < (unsigned)L1D) {
                const int n = idx2d[r * L1D + c];
                s += mem[(size_t)n * MDIM + tt];
            }
        }
    }
    #pragma unroll
    for (int msk = 1; msk < 64; msk <<= 1) s += __shfl_xor(s, msk);
    if (lane == 0) outraw[p] = s;
}

// ---------------------------------------------------------------------------
// K4: divide by global max (single block).
// ---------------------------------------------------------------------------
__global__ __launch_bounds__(256) void norm_kernel(const float* __restrict__ outraw,
                                                   float* __restrict__ out) {
    __shared__ float red[256];
    const int t = threadIdx.x;
    float m = -3.0e38f;
    #pragma unroll
    for (int i = 0; i < 16; ++i) m = fmaxf(m, outraw[t + i * 256]);
    red[t] = m;
    __syncthreads();
    for (int s = 128; s > 0; s >>= 1) {
        if (t < s) red[t] = fmaxf(red[t], red[t + s]);
        __syncthreads();
    }
    const float mx = red[0];
    #pragma unroll
    for (int i = 0; i < 16; ++i) out[t + i * 256] = outraw[t + i * 256] / mx;
}

extern "C" void kernel_launch(void* const* d_in, const int* in_sizes, int n_in,
                              void* d_out, int out_size, void* d_ws, size_t ws_size,
                              hipStream_t stream) {
    const float* img = (const float*)d_in[0];   // 64*64 fp32
    const float* mem = (const float*)d_in[1];   // 16384*225 fp32
    float* out = (float*)d_out;                 // 4096 fp32

    unsigned short* cmh = (unsigned short*)d_ws;              // 4*16384*64 ushort = 8.4 MB
    float* cm32 = (float*)(cmh + (size_t)4 * NMEM * 64);      // 16.8 MB
    float* hn = cm32 + (size_t)4 * NMEM * 64;                 // 16384 f
    unsigned int* hnb = (unsigned int*)(hn + NMEM);           // 16384 u32
    unsigned short* xh = (unsigned short*)(hnb + NMEM);       // 294912 ushort
    float* pcv = (float*)(xh + 294912);                       // 4*256*4608 f = 18.9 MB
    float* pcvT = pcv + (size_t)4 * NBLK * PPAD;              // 18.9 MB
    int* idx2d = (int*)(pcvT + (size_t)4 * NBLK * PPAD);      // 17956 i
    float* outraw = (float*)(idx2d + L1D * L1D);              // 4096 f

    prep_all<<<NMEM / 4, 256, 0, stream>>>(mem, cmh, cm32, hn, hnb);
    prep_x<<<144, 256, 0, stream>>>(img, xh);
    mfma_argmin_kernel<<<dim3(NBLK, 2), 256, 0, stream>>>(cmh, xh, hnb, pcv);
    transpose_kernel<<<dim3(PPAD / 64, NBLK / 64, 4), 256, 0, stream>>>(pcv, pcvT);
    rescue_kernel<<<dim3((MCLS + 3) / 4, 4), 256, 0, stream>>>(img, cm32, hn, pcvT, idx2d);
    fold_kernel<<<1024, 256, 0, stream>>>(mem, idx2d, outraw);
    norm_kernel<<<1, 256, 0, stream>>>(outraw, out);
}

// Round 11
// 182.482 us; speedup vs baseline: 1.1422x; 1.0119x over previous
//
#include <hip/hip_runtime.h>

#define NMEM 16384
#define MDIM 225
#define L1D 134
#define MCLS 4489     // 67*67 real positions per class
#define PPAD 4608     // 144*32 padded positions
#define NBLK 256      // 64-n tiles
#define MARGIN 0.5f

typedef __attribute__((ext_vector_type(8))) _Float16 f16x8;
typedef __attribute__((ext_vector_type(16))) float f32x16;

__device__ inline unsigned short f2h(float f) {
    const _Float16 h = (_Float16)f;
    unsigned short u; __builtin_memcpy(&u, &h, 2); return u;
}
__device__ inline _Float16 us2h(unsigned short u) {
    _Float16 h; __builtin_memcpy(&h, &u, 2); return h;
}
__device__ inline float h2f(unsigned short u) { return (float)us2h(u); }

// ---------------------------------------------------------------------------
// P0 (merged): one wave per n. Stage mem row (225 f) in LDS once; emit
// hn/hnb (wave reduce) and all 4 classes' collapsed filters (fp16 + fp32),
// coalesced 64-wide per class. Reads mem exactly once.
// ---------------------------------------------------------------------------
__global__ __launch_bounds__(256) void prep_all(const float* __restrict__ mem,
                                                unsigned short* __restrict__ cmh,
                                                float* __restrict__ cm32,
                                                float* __restrict__ hn,
                                                unsigned int* __restrict__ hnb) {
    __shared__ float lds[4][240];
    const int wave = threadIdx.x >> 6, lane = threadIdx.x & 63;
    const int n = blockIdx.x * 4 + wave;
    const float* mrow = mem + (size_t)n * MDIM;
    float nrm = 0.f;
    #pragma unroll
    for (int q = 0; q < 4; ++q) {
        const int tt = q * 64 + lane;
        if (tt < MDIM) {
            const float v = mrow[tt];
            lds[wave][tt] = v;
            nrm += v * v;
        }
    }
    __syncthreads();
    #pragma unroll
    for (int m = 1; m < 64; m <<= 1) nrm += __shfl_xor(nrm, m);
    if (lane == 0) {
        const float h = 0.5f * nrm;
        hn[n] = h;
        const unsigned short nh = f2h(-h);
        const unsigned short nl2 = f2h(-h - h2f(nh));
        hnb[n] = (unsigned)nh | ((unsigned)nl2 << 16);
    }
    const int u = lane >> 3, v = lane & 7;
    #pragma unroll
    for (int cls = 0; cls < 4; ++cls) {
        const int er = cls >> 1, ec = cls & 1;
        const int i0 = 2 * u - er, j0 = 2 * v - ec;
        float s = 0.f;
        #pragma unroll
        for (int di = 0; di < 2; ++di) {
            const int i = i0 + di;
            if ((unsigned)i >= 15u) continue;
            #pragma unroll
            for (int dj = 0; dj < 2; ++dj) {
                const int j = j0 + dj;
                if ((unsigned)j >= 15u) continue;
                s += lds[wave][i * 15 + j];
            }
        }
        const size_t o = ((size_t)(cls * NMEM + n)) * 64 + lane;
        cmh[o] = f2h(s);
        cm32[o] = s;
    }
}

// ---------------------------------------------------------------------------
// P2: X (positions) in B-fragment layout, fp16: x[(pt*4+ks)*2+g][lane32][8j].
// ---------------------------------------------------------------------------
__global__ __launch_bounds__(256) void prep_x(const float* __restrict__ img,
                                              unsigned short* __restrict__ xh) {
    const int t = blockIdx.x * 256 + threadIdx.x;   // 144*4*2*32 = 36864
    const int nl = t & 31, g = (t >> 5) & 1, ks = (t >> 6) & 3, pt = t >> 8;
    const int pos = pt * 32 + nl;
    const int u = ks * 2 + g;
    unsigned short h[8];
    if (pos < MCLS) {
        const int mr = pos / 67, mc = pos - mr * 67;
        const int r = mr - 5 + u;
        #pragma unroll
        for (int j = 0; j < 8; ++j) {
            const int c = mc - 5 + j;
            float v = 0.f;
            if ((unsigned)r < 64u && (unsigned)c < 64u) v = img[r * 64 + c];
            h[j] = f2h(v);
        }
    } else {
        #pragma unroll
        for (int j = 0; j < 8; ++j) h[j] = 0;
    }
    #pragma unroll
    for (int j = 0; j < 8; ++j) xh[(size_t)t * 8 + j] = h[j];
}

// ---------------------------------------------------------------------------
// K1: fp16 MFMA scoring, cls-paired to halve the xh L2 stream. Grid
// (256 nblk, 2): block handles cls = 2*cp and 2*cp+1 over the same B tiles.
// A register-resident for both classes; -hn ext K-slice shared (cls-indep).
// B double-buffered (pt = it*4+wave => +8192 halves/iter). Epilogue: plain
// fmax over 64 n per cls, coalesced 4B store pcv[(cls*NBLK+nblk)*PPAD+pos].
// A/B frag: row=lane&31, k=(lane>>5)*8+j. C/D: col=lane&31,
// row=(r&3)+8*(r>>2)+4*(lane>>5)  [HW-verified].
// ---------------------------------------------------------------------------
__global__ __launch_bounds__(256, 2) void mfma_argmin_kernel(const unsigned short* __restrict__ cmh,
                                                             const unsigned short* __restrict__ xh,
                                                             const unsigned int* __restrict__ hnb,
                                                             float* __restrict__ pcv) {
    const int nblk = blockIdx.x, cp = blockIdx.y;
    const int t = threadIdx.x, wave = t >> 6, lane = t & 63;
    const int g = lane >> 5, nl = lane & 31;

    f16x8 a[2][2][4];   // [cls-half][rowgroup][ks]
    #pragma unroll
    for (int h = 0; h < 2; ++h) {
        const int cls = cp * 2 + h;
        #pragma unroll
        for (int ks = 0; ks < 4; ++ks) {
            const size_t base = ((size_t)(cls * NMEM + nblk * 64 + nl)) * 64 + ks * 16 + g * 8;
            a[h][0][ks] = *(const f16x8*)(cmh + base);
            a[h][1][ks] = *(const f16x8*)(cmh + base + 32 * 64);
        }
    }

    const unsigned int hp0 = hnb[nblk * 64 + nl];
    const unsigned int hp1 = hnb[nblk * 64 + 32 + nl];
    f16x8 aex0 = {0,0,0,0,0,0,0,0}, aex1 = {0,0,0,0,0,0,0,0}, bex = {0,0,0,0,0,0,0,0};
    if (g == 0) {
        aex0[0] = us2h((unsigned short)(hp0 & 0xFFFFu));
        aex0[1] = us2h((unsigned short)(hp0 >> 16));
        aex1[0] = us2h((unsigned short)(hp1 & 0xFFFFu));
        aex1[1] = us2h((unsigned short)(hp1 >> 16));
        bex[0] = (_Float16)1.0f;
        bex[1] = (_Float16)1.0f;
    }

    const unsigned short* xp = xh + ((size_t)((wave * 4) * 2 + g)) * 256 + nl * 8;
    float* const orow0 = pcv + (size_t)((cp * 2 + 0) * NBLK + nblk) * PPAD;
    float* const orow1 = pcv + (size_t)((cp * 2 + 1) * NBLK + nblk) * PPAD;

    f16x8 bcur[4], bnxt[4];
    #pragma unroll
    for (int ks = 0; ks < 4; ++ks) bcur[ks] = *(const f16x8*)(xp + ks * 512);

    for (int it = 0; it < 36; ++it) {
        if (it < 35) {
            const unsigned short* xn = xp + 8192;
            #pragma unroll
            for (int ks = 0; ks < 4; ++ks) bnxt[ks] = *(const f16x8*)(xn + ks * 512);
        }

        f32x16 acc[2][2];
        #pragma unroll
        for (int h = 0; h < 2; ++h)
            #pragma unroll
            for (int rg = 0; rg < 2; ++rg)
                #pragma unroll
                for (int r = 0; r < 16; ++r) acc[h][rg][r] = 0.f;

        #pragma unroll
        for (int ks = 0; ks < 4; ++ks)
            #pragma unroll
            for (int h = 0; h < 2; ++h) {
                acc[h][0] = __builtin_amdgcn_mfma_f32_32x32x16_f16(a[h][0][ks], bcur[ks], acc[h][0], 0, 0, 0);
                acc[h][1] = __builtin_amdgcn_mfma_f32_32x32x16_f16(a[h][1][ks], bcur[ks], acc[h][1], 0, 0, 0);
            }
        #pragma unroll
        for (int h = 0; h < 2; ++h) {
            acc[h][0] = __builtin_amdgcn_mfma_f32_32x32x16_f16(aex0, bex, acc[h][0], 0, 0, 0);
            acc[h][1] = __builtin_amdgcn_mfma_f32_32x32x16_f16(aex1, bex, acc[h][1], 0, 0, 0);
        }

        const int pos = (it * 4 + wave) * 32 + nl;
        #pragma unroll
        for (int h = 0; h < 2; ++h) {
            float pm = -3.0e38f;
            #pragma unroll
            for (int r = 0; r < 16; ++r) {
                pm = fmaxf(pm, acc[h][0][r]);
                pm = fmaxf(pm, acc[h][1][r]);
            }
            pm = fmaxf(pm, __shfl_xor(pm, 32));
            if (g == 0) (h ? orow1 : orow0)[pos] = pm;
        }

        xp += 8192;
        #pragma unroll
        for (int ks = 0; ks < 4; ++ks) bcur[ks] = bnxt[ks];
    }
}

// ---------------------------------------------------------------------------
// T1: transpose pcv (4, NBLK, PPAD) -> pcvT (4, PPAD, NBLK), float4 both
// global sides. Grid (PPAD/64, NBLK/64, 4).
// ---------------------------------------------------------------------------
__global__ __launch_bounds__(256) void transpose_kernel(const float* __restrict__ in,
                                                        float* __restrict__ out) {
    __shared__ float tile[64][65];
    const int pb = blockIdx.x, tb = blockIdx.y, cls = blockIdx.z;
    const int t = threadIdx.x;
    const int c4 = t & 15, r0 = t >> 4;
    #pragma unroll
    for (int rr = 0; rr < 4; ++rr) {
        const int row = r0 + rr * 16;
        const float4 v = *(const float4*)(in + ((size_t)(cls * NBLK + tb * 64 + row)) * PPAD + pb * 64 + c4 * 4);
        tile[row][c4 * 4 + 0] = v.x;
        tile[row][c4 * 4 + 1] = v.y;
        tile[row][c4 * 4 + 2] = v.z;
        tile[row][c4 * 4 + 3] = v.w;
    }
    __syncthreads();
    #pragma unroll
    for (int rr = 0; rr < 4; ++rr) {
        const int p = r0 + rr * 16;
        float4 v;
        v.x = tile[c4 * 4 + 0][p];
        v.y = tile[c4 * 4 + 1][p];
        v.z = tile[c4 * 4 + 2][p];
        v.w = tile[c4 * 4 + 3][p];
        *(float4*)(out + ((size_t)(cls * PPAD + pb * 64 + p)) * NBLK + tb * 64 + c4 * 4) = v;
    }
}

// ---------------------------------------------------------------------------
// T2: transpose cm32 (4, NMEM, 64) -> cmT (4, 64, NMEM), float4 both global
// sides, 64x64 tiles. Grid (NMEM/64, 4). Gives rescue a k-major layout whose
// lane-stride is 4 B (4 lines/load) instead of 256 B (64 lines/load).
// ---------------------------------------------------------------------------
__global__ __launch_bounds__(256) void transpose_cm(const float* __restrict__ in,
                                                    float* __restrict__ out) {
    __shared__ float tile[64][65];
    const int nb = blockIdx.x, cls = blockIdx.y;
    const int t = threadIdx.x;
    const int c4 = t & 15, r0 = t >> 4;
    #pragma unroll
    for (int rr = 0; rr < 4; ++rr) {
        const int row = r0 + rr * 16;   // n-local
        const float4 v = *(const float4*)(in + ((size_t)(cls * NMEM + nb * 64 + row)) * 64 + c4 * 4);
        tile[row][c4 * 4 + 0] = v.x;
        tile[row][c4 * 4 + 1] = v.y;
        tile[row][c4 * 4 + 2] = v.z;
        tile[row][c4 * 4 + 3] = v.w;
    }
    __syncthreads();
    #pragma unroll
    for (int rr = 0; rr < 4; ++rr) {
        const int k = r0 + rr * 16;
        float4 v;
        v.x = tile[c4 * 4 + 0][k];
        v.y = tile[c4 * 4 + 1][k];
        v.z = tile[c4 * 4 + 2][k];
        v.w = tile[c4 * 4 + 3][k];
        *(float4*)(out + ((size_t)(cls * 64 + k)) * NMEM + nb * 64 + c4 * 4) = v;
    }
}

// ---------------------------------------------------------------------------
// K2: rescue, one wave per (cls, pos). Coalesced row read of 256 tile-maxes
// from pcvT, shfl-max vmax, ballot tiles within MARGIN, exact fp32 rescore
// of ALL 64 n per candidate tile from k-major cmT (lane n = nblk*64+lane,
// coalesced 4B lane-stride; x broadcast via shfl; 4 split accumulators).
// Butterfly argmax with lowest-n tie (argmin-first).
// ---------------------------------------------------------------------------
__global__ __launch_bounds__(256) void rescue_kernel(const float* __restrict__ img,
                                                     const float* __restrict__ cmT,
                                                     const float* __restrict__ hn,
                                                     const float* __restrict__ pcvT,
                                                     int* __restrict__ idx2d) {
    const int wave = threadIdx.x >> 6, lane = threadIdx.x & 63;
    const int cls = blockIdx.y;
    const int pos = blockIdx.x * 4 + wave;
    if (pos >= MCLS) return;
    const int er = cls >> 1, ec = cls & 1;
    const int mr = pos / 67, mc = pos - mr * 67;

    // per-lane x value, lane = u*8+v == k index of the collapsed filters.
    const int xr = mr - 5 + (lane >> 3), xc = mc - 5 + (lane & 7);
    const float xv = ((unsigned)xr < 64u && (unsigned)xc < 64u) ? img[xr * 64 + xc] : 0.f;

    // vals[s] = tile-max of nblk = lane*4+s  (contiguous row read).
    const float* row = pcvT + ((size_t)(cls * PPAD + pos)) * NBLK + lane * 4;
    const float4 v4 = *(const float4*)row;
    float vals[4] = {v4.x, v4.y, v4.z, v4.w};

    float vmax = fmaxf(fmaxf(vals[0], vals[1]), fmaxf(vals[2], vals[3]));
    #pragma unroll
    for (int m = 1; m < 64; m <<= 1) vmax = fmaxf(vmax, __shfl_xor(vmax, m));
    const float thr = vmax - MARGIN;

    const float* cbase = cmT + (size_t)cls * 64 * NMEM;

    float best = -3.0e38f; int bn = 0x7FFFFFFF;
    #pragma unroll
    for (int s = 0; s < 4; ++s) {
        unsigned long long bal = __ballot(vals[s] >= thr);
        while (bal) {
            const int src = __ffsll((long long)bal) - 1;
            bal &= bal - 1;
            const int nblk = src * 4 + s;
            const int n = nblk * 64 + lane;                 // this lane's column
            const float* cp = cbase + n;
            float a0 = 0.f, a1 = 0.f, a2 = 0.f, a3 = 0.f;
            #pragma unroll
            for (int k2 = 0; k2 < 16; ++k2) {
                a0 = fmaf(cp[(size_t)(k2) * NMEM],      __shfl(xv, k2),      a0);
                a1 = fmaf(cp[(size_t)(k2 + 16) * NMEM], __shfl(xv, k2 + 16), a1);
                a2 = fmaf(cp[(size_t)(k2 + 32) * NMEM], __shfl(xv, k2 + 32), a2);
                a3 = fmaf(cp[(size_t)(k2 + 48) * NMEM], __shfl(xv, k2 + 48), a3);
            }
            const float sc = (a0 + a1) + (a2 + a3) - hn[n];
            if (sc > best || (sc == best && n < bn)) { best = sc; bn = n; }
        }
    }
    #pragma unroll
    for (int m = 1; m < 64; m <<= 1) {
        const float ob = __shfl_xor(best, m);
        const int onb = __shfl_xor(bn, m);
        if (ob > best || (ob == best && onb < bn)) { best = ob; bn = onb; }
    }
    if (lane == 0) idx2d[(er + 2 * mr) * L1D + (ec + 2 * mc)] = bn;
}

// ---------------------------------------------------------------------------
// K3: fold, one wave per output pixel.
// ---------------------------------------------------------------------------
__global__ __launch_bounds__(256) void fold_kernel(const float* __restrict__ mem,
                                                   const int* __restrict__ idx2d,
                                                   float* __restrict__ outraw) {
    const int wave = threadIdx.x >> 6, lane = threadIdx.x & 63;
    const int p = blockIdx.x * 4 + wave;   // 0..4095
    const int oi = p >> 6, oj = p & 63;
    float s = 0.f;
    #pragma unroll
    for (int tb = 0; tb < 256; tb += 64) {
        const int tt = tb + lane;
        if (tt < MDIM) {
            const int a = tt / 15, b = tt - 15 * a;
            const int r = 10 + 2 * oi - a, c = 10 + 2 * oj - b;
            if ((unsigned)r < (unsigned)L1D && (unsigned)c < (unsigned)L1D) {
                const int n = idx2d[r * L1D + c];
                s += mem[(size_t)n * MDIM + tt];
            }
        }
    }
    #pragma unroll
    for (int msk = 1; msk < 64; msk <<= 1) s += __shfl_xor(s, msk);
    if (lane == 0) outraw[p] = s;
}

// ---------------------------------------------------------------------------
// K4: divide by global max (single block).
// ---------------------------------------------------------------------------
__global__ __launch_bounds__(256) void norm_kernel(const float* __restrict__ outraw,
                                                   float* __restrict__ out) {
    __shared__ float red[256];
    const int t = threadIdx.x;
    float m = -3.0e38f;
    #pragma unroll
    for (int i = 0; i < 16; ++i) m = fmaxf(m, outraw[t + i * 256]);
    red[t] = m;
    __syncthreads();
    for (int s = 128; s > 0; s >>= 1) {
        if (t < s) red[t] = fmaxf(red[t], red[t + s]);
        __syncthreads();
    }
    const float mx = red[0];
    #pragma unroll
    for (int i = 0; i < 16; ++i) out[t + i * 256] = outraw[t + i * 256] / mx;
}

extern "C" void kernel_launch(void* const* d_in, const int* in_sizes, int n_in,
                              void* d_out, int out_size, void* d_ws, size_t ws_size,
                              hipStream_t stream) {
    const float* img = (const float*)d_in[0];   // 64*64 fp32
    const float* mem = (const float*)d_in[1];   // 16384*225 fp32
    float* out = (float*)d_out;                 // 4096 fp32

    unsigned short* cmh = (unsigned short*)d_ws;              // 4*16384*64 ushort = 8.4 MB
    float* cm32 = (float*)(cmh + (size_t)4 * NMEM * 64);      // 16.8 MB
    float* cmT = cm32 + (size_t)4 * NMEM * 64;                // 16.8 MB (k-major)
    float* hn = cmT + (size_t)4 * NMEM * 64;                  // 16384 f
    unsigned int* hnb = (unsigned int*)(hn + NMEM);           // 16384 u32
    unsigned short* xh = (unsigned short*)(hnb + NMEM);       // 294912 ushort
    float* pcv = (float*)(xh + 294912);                       // 4*256*4608 f = 18.9 MB
    float* pcvT = pcv + (size_t)4 * NBLK * PPAD;              // 18.9 MB
    int* idx2d = (int*)(pcvT + (size_t)4 * NBLK * PPAD);      // 17956 i
    float* outraw = (float*)(idx2d + L1D * L1D);              // 4096 f

    prep_all<<<NMEM / 4, 256, 0, stream>>>(mem, cmh, cm32, hn, hnb);
    prep_x<<<144, 256, 0, stream>>>(img, xh);
    mfma_argmin_kernel<<<dim3(NBLK, 2), 256, 0, stream>>>(cmh, xh, hnb, pcv);
    transpose_cm<<<dim3(NMEM / 64, 4), 256, 0, stream>>>(cm32, cmT);
    transpose_kernel<<<dim3(PPAD / 64, NBLK / 64, 4), 256, 0, stream>>>(pcv, pcvT);
    rescue_kernel<<<dim3((MCLS + 3) / 4, 4), 256, 0, stream>>>(img, cmT, hn, pcvT, idx2d);
    fold_kernel<<<1024, 256, 0, stream>>>(mem, idx2d, outraw);
    norm_kernel<<<1, 256, 0, stream>>>(outraw, out);
}